// Round 3
// baseline (190.935 us; speedup 1.0000x reference)
//
#include <hip/hip_runtime.h>
#include <hip/hip_bf16.h>
#include <stdint.h>

using bf16 = __hip_bfloat16;
typedef __attribute__((ext_vector_type(8))) __bf16 bf16x8;
typedef __attribute__((ext_vector_type(4))) float f32x4;

static __device__ __forceinline__ bf16 f2b(float x) { return __float2bfloat16(x); }
static __device__ __forceinline__ uint32_t pack2(float a, float b) {
    bf16 ha = f2b(a), hb = f2b(b);
    return (uint32_t)(*(const uint16_t*)&ha) | ((uint32_t)(*(const uint16_t*)&hb) << 16);
}

// =====================================================================
// Kernel 1 (single dispatch), block-uniform branches:
//  [0, nbVal)            value fp32->bf16, 8 elems/thread
//  [+nbWv)               Wv    fp32->bf16
//  [+nbBc)               bc[i] = Wo[i,:].bv + bo[i]   (4 rows/block, 1 row/wave)
//  [+nbWc)               Wc = Wo @ Wv (64x64 tile/block, reads fp32 directly,
//                        casts+transposes in LDS; writes bf16 Wc_b)
// =====================================================================
__global__ __launch_bounds__(256) void prep_wc_kernel(
    const float* __restrict__ value, const float* __restrict__ Wv,
    const float* __restrict__ Wo, const float* __restrict__ bv,
    const float* __restrict__ bo,
    bf16* __restrict__ value_b, bf16* __restrict__ Wv_b,
    bf16* __restrict__ Wc_b, float* __restrict__ bc,
    int nbVal, int nbWv, int nbBc, int dm)
{
    __shared__ bf16 dAs[64 * 40];   // padded stride 40 elems (80 B)
    __shared__ bf16 dBs[64 * 40];

    const int b = blockIdx.x;
    const int tid = threadIdx.x;

    if (b < nbVal) {                                  // ---- value cast
        const size_t i = ((size_t)b * 256 + tid) * 8;
        const float4 v0 = *(const float4*)(value + i);
        const float4 v1 = *(const float4*)(value + i + 4);
        uint4 u = { pack2(v0.x, v0.y), pack2(v0.z, v0.w),
                    pack2(v1.x, v1.y), pack2(v1.z, v1.w) };
        *(uint4*)(value_b + i) = u;
    } else if (b < nbVal + nbWv) {                    // ---- Wv cast
        const size_t i = ((size_t)(b - nbVal) * 256 + tid) * 8;
        const float4 v0 = *(const float4*)(Wv + i);
        const float4 v1 = *(const float4*)(Wv + i + 4);
        uint4 u = { pack2(v0.x, v0.y), pack2(v0.z, v0.w),
                    pack2(v1.x, v1.y), pack2(v1.z, v1.w) };
        *(uint4*)(Wv_b + i) = u;
    } else if (b < nbVal + nbWv + nbBc) {             // ---- bc
        const int lane = tid & 63;
        const int wave = tid >> 6;
        const int row = (b - nbVal - nbWv) * 4 + wave;
        const float* wrow = Wo + (size_t)row * dm;
        float s = 0.f;
        for (int k = lane * 4; k < dm; k += 256) {
            const float4 w = *(const float4*)(wrow + k);
            const float4 x = *(const float4*)(bv + k);
            s += w.x * x.x + w.y * x.y + w.z * x.z + w.w * x.w;
        }
        #pragma unroll
        for (int off = 32; off >= 1; off >>= 1) s += __shfl_down(s, off, 64);
        if (lane == 0) bc[row] = s + bo[row];
    } else {                                          // ---- Wc 64x64 tile
        const int t = b - nbVal - nbWv - nbBc;
        const int tpr = dm / 64;
        const int bm = (t / tpr) * 64, bn = (t % tpr) * 64;
        const int lane = tid & 63;
        const int wave = tid >> 6;
        const int wm = (wave >> 1) * 32, wn = (wave & 1) * 32;
        const int fr = lane & 15;
        const int fkc = lane >> 4;

        f32x4 acc[2][2] = {};

        for (int k0 = 0; k0 < dm; k0 += 32) {
            // stage A = Wo[bm..+63][k0..+31], cast to bf16
            {
                const int r = tid >> 2, col = (tid & 3) * 8;
                const float4 v0 = *(const float4*)(Wo + (size_t)(bm + r) * dm + k0 + col);
                const float4 v1 = *(const float4*)(Wo + (size_t)(bm + r) * dm + k0 + col + 4);
                uint4 u = { pack2(v0.x, v0.y), pack2(v0.z, v0.w),
                            pack2(v1.x, v1.y), pack2(v1.z, v1.w) };
                *(uint4*)(dAs + r * 40 + col) = u;
            }
            // stage B[n][k] = Wv[k0+kk][bn+n] (transpose + cast)
            #pragma unroll
            for (int q = 0; q < 2; ++q) {
                const int fidx = tid + q * 256;          // 0..511
                const int kk = fidx >> 4, c4 = (fidx & 15) * 4;
                const float4 v = *(const float4*)(Wv + (size_t)(k0 + kk) * dm + bn + c4);
                dBs[(c4 + 0) * 40 + kk] = f2b(v.x);
                dBs[(c4 + 1) * 40 + kk] = f2b(v.y);
                dBs[(c4 + 2) * 40 + kk] = f2b(v.z);
                dBs[(c4 + 3) * 40 + kk] = f2b(v.w);
            }
            __syncthreads();
            bf16x8 af[2], bg[2];
            #pragma unroll
            for (int u = 0; u < 2; ++u) {
                af[u] = *(const bf16x8*)(dAs + (wm + u * 16 + fr) * 40 + fkc * 8);
                bg[u] = *(const bf16x8*)(dBs + (wn + u * 16 + fr) * 40 + fkc * 8);
            }
            #pragma unroll
            for (int i = 0; i < 2; ++i)
                #pragma unroll
                for (int j = 0; j < 2; ++j)
                    acc[i][j] = __builtin_amdgcn_mfma_f32_16x16x32_bf16(
                        af[i], bg[j], acc[i][j], 0, 0, 0);
            __syncthreads();
        }
        const int quad = lane >> 4;
        #pragma unroll
        for (int j = 0; j < 2; ++j) {
            const int col = bn + wn + j * 16 + fr;
            #pragma unroll
            for (int i = 0; i < 2; ++i) {
                const int row0 = bm + wm + i * 16 + quad * 4;
                #pragma unroll
                for (int r = 0; r < 4; ++r)
                    Wc_b[(size_t)(row0 + r) * dm + col] = f2b(acc[i][j][r]);
            }
        }
    }
}

// =====================================================================
// Big fused GEMM: C = value_b @ Bcat^T, Bcat = [Wv_b ; Wc_b] (2*dm x dm).
// bn < dm -> out1 & out2 (+bv); bn >= dm -> out0 (+bc).
// XOR-swizzled LDS (slot s holds kpart p = (s&3)^(r&3)^((r>>2)&3)) kills the
// 8-way ds_read_b128 bank conflicts while keeping global_load_lds's
// contiguous lane->LDS mapping. Epilogue stages 16x64 slabs per wave through
// padded LDS (stride 68 floats) -> float4 coalesced stores.
// =====================================================================
#define TM 128
#define TN 128
#define BK 32

__global__ __launch_bounds__(256) void gemm_fused(
    const bf16* __restrict__ A, const bf16* __restrict__ Bcat,
    const float* __restrict__ bv, const float* __restrict__ bc,
    float* __restrict__ out0, float* __restrict__ out1, float* __restrict__ out2,
    int M, int dm)
{
    __shared__ bf16 As[TM * BK];          // 8 KB
    __shared__ bf16 Bs[TN * BK];          // 8 KB
    __shared__ float Es[4][16 * 68];      // epilogue staging, 4352 B/wave

    const int K = dm;
    const int tid = threadIdx.x;
    const int lane = tid & 63;
    const int wave = tid >> 6;
    const int wm = (wave >> 1) * 64;
    const int wn = (wave & 1) * 64;
    const int bm = blockIdx.x * TM;
    const int bn = blockIdx.y * TN;

    f32x4 acc[4][4] = {};

    // swizzled staging pointers (slot -> permuted kpart)
    const int s0 = wave * 128 + lane;
    const int s1 = s0 + 64;
    const int r0 = s0 >> 2, r1 = s1 >> 2;
    const int p0 = (s0 & 3) ^ (r0 & 3) ^ ((r0 >> 2) & 3);
    const int p1 = (s1 & 3) ^ (r1 & 3) ^ ((r1 >> 2) & 3);
    const bf16* gA0 = A + (size_t)(bm + r0) * K + p0 * 8;
    const bf16* gA1 = A + (size_t)(bm + r1) * K + p1 * 8;
    const bf16* gB0 = Bcat + (size_t)(bn + r0) * K + p0 * 8;
    const bf16* gB1 = Bcat + (size_t)(bn + r1) * K + p1 * 8;
    bf16* lA0 = As + s0 * 8;
    bf16* lA1 = As + s1 * 8;
    bf16* lB0 = Bs + s0 * 8;
    bf16* lB1 = Bs + s1 * 8;

    const int fr = lane & 15;
    const int fkc = lane >> 4;
    const int xsw = fkc ^ (fr & 3) ^ ((fr >> 2) & 3);   // reader swizzle

    for (int k0 = 0; k0 < K; k0 += BK) {
        __builtin_amdgcn_global_load_lds(
            (const __attribute__((address_space(1))) void*)(gA0 + k0),
            (__attribute__((address_space(3))) void*)lA0, 16, 0, 0);
        __builtin_amdgcn_global_load_lds(
            (const __attribute__((address_space(1))) void*)(gA1 + k0),
            (__attribute__((address_space(3))) void*)lA1, 16, 0, 0);
        __builtin_amdgcn_global_load_lds(
            (const __attribute__((address_space(1))) void*)(gB0 + k0),
            (__attribute__((address_space(3))) void*)lB0, 16, 0, 0);
        __builtin_amdgcn_global_load_lds(
            (const __attribute__((address_space(1))) void*)(gB1 + k0),
            (__attribute__((address_space(3))) void*)lB1, 16, 0, 0);
        __syncthreads();

        bf16x8 af[4], bg[4];
        #pragma unroll
        for (int t = 0; t < 4; ++t) {
            af[t] = *(const bf16x8*)(As + (wm + t * 16 + fr) * BK + xsw * 8);
            bg[t] = *(const bf16x8*)(Bs + (wn + t * 16 + fr) * BK + xsw * 8);
        }
        #pragma unroll
        for (int i = 0; i < 4; ++i)
            #pragma unroll
            for (int j = 0; j < 4; ++j)
                acc[i][j] = __builtin_amdgcn_mfma_f32_16x16x32_bf16(
                    af[i], bg[j], acc[i][j], 0, 0, 0);
        __syncthreads();
    }

    // ---------------- epilogue ----------------
    const bool second = (bn >= dm);                // block-uniform
    const int colbase = bn + wn - (second ? dm : 0);
    const float* bias = second ? bc : bv;
    float* o0 = second ? out0 : out1;
    float* o1 = second ? nullptr : out2;

    float bb[4];
    #pragma unroll
    for (int j = 0; j < 4; ++j) bb[j] = bias[colbase + j * 16 + fr];

    float* E = &Es[wave][0];
    const int quad = lane >> 4;
    const int rgrp = lane >> 4;          // read-phase row group
    const int cc = (lane & 15) * 4;      // read-phase col

    #pragma unroll
    for (int i = 0; i < 4; ++i) {
        // scatter slab i into padded LDS (2-way max, free)
        #pragma unroll
        for (int j = 0; j < 4; ++j)
            #pragma unroll
            for (int r = 0; r < 4; ++r)
                E[(quad * 4 + r) * 68 + j * 16 + fr] = acc[i][j][r] + bb[j];
        // wave-private region: in-order DS pipe + compiler lgkmcnt, no barrier
        #pragma unroll
        for (int ph = 0; ph < 4; ++ph) {
            const int row = rgrp * 4 + ph;
            const float4 v = *(const float4*)(E + row * 68 + cc);
            const size_t gi = (size_t)(bm + wm + i * 16 + row) * dm + colbase + cc;
            *(float4*)(o0 + gi) = v;
            if (o1) *(float4*)(o1 + gi) = v;
        }
    }
}

// ---------------- fp32 fallback (no workspace needed) ----------------
__global__ __launch_bounds__(256) void gemm_f32_naive(
    const float* __restrict__ A, const float* __restrict__ B,
    const float* __restrict__ bias,
    float* __restrict__ C0, float* __restrict__ C1,
    int M, int N, int K)
{
    const size_t idx = (size_t)blockIdx.x * 256 + threadIdx.x;
    if (idx >= (size_t)M * N) return;
    const int row = (int)(idx / N), col = (int)(idx % N);
    const float* a = A + (size_t)row * K;
    const float* b = B + (size_t)col * K;
    float s = bias ? bias[col] : 0.0f;
    for (int k = 0; k < K; ++k) s += a[k] * b[k];
    C0[idx] = s;
    if (C1) C1[idx] = s;
}

// Math: softmax row-sums are exactly 1 => x=y=z=v (value projection).
//   out1 = out2 = value @ Wv^T + bv
//   out0 = value @ (Wo@Wv)^T + (Wo@bv + bo)
// Two dispatches: (1) casts + bc + Wc, (2) one 4096x2048x1024 bf16 GEMM.
extern "C" void kernel_launch(void* const* d_in, const int* in_sizes, int n_in,
                              void* d_out, int out_size, void* d_ws, size_t ws_size,
                              hipStream_t stream)
{
    const float* value = (const float*)d_in[2];
    const float* Wv    = (const float*)d_in[7];
    const float* bv    = (const float*)d_in[8];
    const float* Wo    = (const float*)d_in[9];
    const float* bo    = (const float*)d_in[10];

    const int dm = in_sizes[8];              // 1024
    const int M  = in_sizes[2] / dm;         // 4096
    const size_t MN = (size_t)M * dm;

    float* out0 = (float*)d_out;
    float* out1 = out0 + MN;
    float* out2 = out1 + MN;

    // ws: value_b | Wv_b | Wc_b (Wv_b..Wc_b contiguous = Bcat) | bc
    const size_t need = MN * 2 + (size_t)dm * dm * 2 * 2 + (size_t)dm * 4;
    const bool ok = (ws_size >= need) && (M % TM == 0) && (dm % TM == 0) &&
                    (MN % 2048 == 0) && ((size_t)dm * dm % 2048 == 0) &&
                    (dm % 64 == 0) && (dm % 4 == 0);
    if (ok) {
        char* ws = (char*)d_ws;
        bf16* value_b = (bf16*)ws;                    ws += MN * 2;
        bf16* Wv_b    = (bf16*)ws;                    ws += (size_t)dm * dm * 2;
        bf16* Wc_b    = (bf16*)ws;                    ws += (size_t)dm * dm * 2;
        float* bc     = (float*)ws;

        const int nbVal = (int)(MN / 2048);
        const int nbWv  = (int)((size_t)dm * dm / 2048);
        const int nbBc  = dm / 4;
        const int nbWc  = (dm / 64) * (dm / 64);
        prep_wc_kernel<<<nbVal + nbWv + nbBc + nbWc, 256, 0, stream>>>(
            value, Wv, Wo, bv, bo, value_b, Wv_b, Wc_b, bc,
            nbVal, nbWv, nbBc, dm);

        dim3 grid(M / TM, 2 * dm / TN);
        gemm_fused<<<grid, 256, 0, stream>>>(value_b, Wv_b /* = Bcat head */,
                                             bv, bc, out0, out1, out2, M, dm);
    } else {
        const int nblk = (int)((MN + 255) / 256);
        gemm_f32_naive<<<nblk, 256, 0, stream>>>(value, Wv, bv, out1, out2, M, dm, dm);
        gemm_f32_naive<<<nblk, 256, 0, stream>>>(out1, Wo, bo, out0, nullptr, M, dm, dm);
    }
}

// Round 4
// 160.003 us; speedup vs baseline: 1.1933x; 1.1933x over previous
//
#include <hip/hip_runtime.h>
#include <hip/hip_bf16.h>
#include <stdint.h>

using bf16 = __hip_bfloat16;
typedef __attribute__((ext_vector_type(8))) __bf16 bf16x8;
typedef __attribute__((ext_vector_type(4))) float f32x4;

static __device__ __forceinline__ bf16 f2b(float x) { return __float2bfloat16(x); }
static __device__ __forceinline__ uint32_t pack2(float a, float b) {
    bf16 ha = f2b(a), hb = f2b(b);
    return (uint32_t)(*(const uint16_t*)&ha) | ((uint32_t)(*(const uint16_t*)&hb) << 16);
}

// =====================================================================
// prep (pure bandwidth, one dispatch, block-uniform branches):
//  [0,nbVal)   value fp32->bf16 (8/thread)
//  [+nbWv)     Wv cast
//  [+nbWo)     Wo cast
//  [+nbT)      WvT_b[j][i] = bf16(Wv[i][j])   (32x32 tile, padded LDS)
//  [+nbBc)     bc[i] = Wo[i,:].bv + bo[i]     (4 rows/block, 1 row/wave)
// =====================================================================
__global__ __launch_bounds__(256) void prep_kernel(
    const float* __restrict__ value, const float* __restrict__ Wv,
    const float* __restrict__ Wo, const float* __restrict__ bv,
    const float* __restrict__ bo,
    bf16* __restrict__ value_b, bf16* __restrict__ Wv_b,
    bf16* __restrict__ Wo_b, bf16* __restrict__ WvT_b, float* __restrict__ bc,
    int nbVal, int nbWv, int nbWo, int nbT, int dm)
{
    __shared__ bf16 tile[32][34];   // +2 pad: write & read conflict-free
    const int b = blockIdx.x;
    const int tid = threadIdx.x;

    if (b < nbVal) {
        const size_t i = ((size_t)b * 256 + tid) * 8;
        const float4 v0 = *(const float4*)(value + i);
        const float4 v1 = *(const float4*)(value + i + 4);
        uint4 u = { pack2(v0.x, v0.y), pack2(v0.z, v0.w),
                    pack2(v1.x, v1.y), pack2(v1.z, v1.w) };
        *(uint4*)(value_b + i) = u;
    } else if (b < nbVal + nbWv) {
        const size_t i = ((size_t)(b - nbVal) * 256 + tid) * 8;
        const float4 v0 = *(const float4*)(Wv + i);
        const float4 v1 = *(const float4*)(Wv + i + 4);
        uint4 u = { pack2(v0.x, v0.y), pack2(v0.z, v0.w),
                    pack2(v1.x, v1.y), pack2(v1.z, v1.w) };
        *(uint4*)(Wv_b + i) = u;
    } else if (b < nbVal + nbWv + nbWo) {
        const size_t i = ((size_t)(b - nbVal - nbWv) * 256 + tid) * 8;
        const float4 v0 = *(const float4*)(Wo + i);
        const float4 v1 = *(const float4*)(Wo + i + 4);
        uint4 u = { pack2(v0.x, v0.y), pack2(v0.z, v0.w),
                    pack2(v1.x, v1.y), pack2(v1.z, v1.w) };
        *(uint4*)(Wo_b + i) = u;
    } else if (b < nbVal + nbWv + nbWo + nbT) {
        const int t = b - nbVal - nbWv - nbWo;
        const int tpr = dm / 32;
        const int i0 = (t / tpr) * 32, j0 = (t % tpr) * 32;
        const int tx = tid & 31, ty = tid >> 5;      // ty 0..7
        #pragma unroll
        for (int p = 0; p < 4; ++p) {
            const int r = ty + p * 8;
            tile[r][tx] = f2b(Wv[(size_t)(i0 + r) * dm + j0 + tx]);
        }
        __syncthreads();
        #pragma unroll
        for (int p = 0; p < 4; ++p) {
            const int c = ty + p * 8;
            WvT_b[(size_t)(j0 + c) * dm + i0 + tx] = tile[tx][c];
        }
    } else {
        const int lane = tid & 63;
        const int wave = tid >> 6;
        const int row = (b - nbVal - nbWv - nbWo - nbT) * 4 + wave;
        const float* wrow = Wo + (size_t)row * dm;
        float s = 0.f;
        for (int k = lane * 4; k < dm; k += 256) {
            const float4 w = *(const float4*)(wrow + k);
            const float4 x = *(const float4*)(bv + k);
            s += w.x * x.x + w.y * x.y + w.z * x.z + w.w * x.w;
        }
        #pragma unroll
        for (int off = 32; off >= 1; off >>= 1) s += __shfl_down(s, off, 64);
        if (lane == 0) bc[row] = s + bo[row];
    }
}

// =====================================================================
// wc_gemm: Wc = Wo @ Wv via A=Wo_b (dm x K), B=WvT_b (dm x K), C=A@B^T.
// 64x64 tile, BK=64 (16 k-iters), global_load_lds width-16, XOR swizzle:
// slot s (row r=s>>3, 8 parts of 16B) stores part (s&7)^(r&7); reader
// xsw=(kk*4+fkc)^(fr&7) -> 2-way banks (free). Output bf16.
// =====================================================================
__global__ __launch_bounds__(256) void wc_gemm(
    const bf16* __restrict__ A, const bf16* __restrict__ B,
    bf16* __restrict__ C, int N, int K)
{
    __shared__ bf16 As[64 * 64];   // 8 KB
    __shared__ bf16 Bs[64 * 64];

    const int tid = threadIdx.x;
    const int lane = tid & 63;
    const int wave = tid >> 6;
    const int wm = (wave >> 1) * 32;
    const int wn = (wave & 1) * 32;
    const int bm = blockIdx.x * 64;
    const int bn = blockIdx.y * 64;

    f32x4 acc[2][2] = {};

    const int s0 = wave * 128 + lane;
    const int s1 = s0 + 64;
    const int r0 = s0 >> 3, r1 = s1 >> 3;
    const int p0 = (s0 & 7) ^ (r0 & 7);
    const int p1 = (s1 & 7) ^ (r1 & 7);
    const bf16* gA0 = A + (size_t)(bm + r0) * K + p0 * 8;
    const bf16* gA1 = A + (size_t)(bm + r1) * K + p1 * 8;
    const bf16* gB0 = B + (size_t)(bn + r0) * K + p0 * 8;
    const bf16* gB1 = B + (size_t)(bn + r1) * K + p1 * 8;
    bf16* lA0 = As + s0 * 8;
    bf16* lA1 = As + s1 * 8;
    bf16* lB0 = Bs + s0 * 8;
    bf16* lB1 = Bs + s1 * 8;

    const int fr = lane & 15;
    const int fkc = lane >> 4;

    for (int k0 = 0; k0 < K; k0 += 64) {
        __builtin_amdgcn_global_load_lds(
            (const __attribute__((address_space(1))) void*)(gA0 + k0),
            (__attribute__((address_space(3))) void*)lA0, 16, 0, 0);
        __builtin_amdgcn_global_load_lds(
            (const __attribute__((address_space(1))) void*)(gA1 + k0),
            (__attribute__((address_space(3))) void*)lA1, 16, 0, 0);
        __builtin_amdgcn_global_load_lds(
            (const __attribute__((address_space(1))) void*)(gB0 + k0),
            (__attribute__((address_space(3))) void*)lB0, 16, 0, 0);
        __builtin_amdgcn_global_load_lds(
            (const __attribute__((address_space(1))) void*)(gB1 + k0),
            (__attribute__((address_space(3))) void*)lB1, 16, 0, 0);
        __syncthreads();

        #pragma unroll
        for (int kk = 0; kk < 2; ++kk) {
            const int xsw = ((kk * 4 + fkc) ^ (fr & 7)) * 8;
            bf16x8 af[2], bg[2];
            #pragma unroll
            for (int u = 0; u < 2; ++u) {
                af[u] = *(const bf16x8*)(As + (wm + u * 16 + fr) * 64 + xsw);
                bg[u] = *(const bf16x8*)(Bs + (wn + u * 16 + fr) * 64 + xsw);
            }
            #pragma unroll
            for (int i = 0; i < 2; ++i)
                #pragma unroll
                for (int j = 0; j < 2; ++j)
                    acc[i][j] = __builtin_amdgcn_mfma_f32_16x16x32_bf16(
                        af[i], bg[j], acc[i][j], 0, 0, 0);
        }
        __syncthreads();
    }

    const int quad = lane >> 4;
    #pragma unroll
    for (int j = 0; j < 2; ++j) {
        const int col = bn + wn + j * 16 + fr;
        #pragma unroll
        for (int i = 0; i < 2; ++i) {
            const int row0 = bm + wm + i * 16 + quad * 4;
            #pragma unroll
            for (int r = 0; r < 4; ++r)
                C[(size_t)(row0 + r) * N + col] = f2b(acc[i][j][r]);
        }
    }
}

// =====================================================================
// Big fused GEMM (unchanged from R3): C = value_b @ Bcat^T,
// Bcat=[Wv_b;Wc_b]. bn<dm -> out1&out2 (+bv); else out0 (+bc).
// XOR-swizzled LDS + padded-LDS float4 epilogue.
// =====================================================================
#define TM 128
#define TN 128
#define BK 32

__global__ __launch_bounds__(256) void gemm_fused(
    const bf16* __restrict__ A, const bf16* __restrict__ Bcat,
    const float* __restrict__ bv, const float* __restrict__ bc,
    float* __restrict__ out0, float* __restrict__ out1, float* __restrict__ out2,
    int M, int dm)
{
    __shared__ bf16 As[TM * BK];
    __shared__ bf16 Bs[TN * BK];
    __shared__ float Es[4][16 * 68];

    const int K = dm;
    const int tid = threadIdx.x;
    const int lane = tid & 63;
    const int wave = tid >> 6;
    const int wm = (wave >> 1) * 64;
    const int wn = (wave & 1) * 64;
    const int bm = blockIdx.x * TM;
    const int bn = blockIdx.y * TN;

    f32x4 acc[4][4] = {};

    const int s0 = wave * 128 + lane;
    const int s1 = s0 + 64;
    const int r0 = s0 >> 2, r1 = s1 >> 2;
    const int p0 = (s0 & 3) ^ (r0 & 3) ^ ((r0 >> 2) & 3);
    const int p1 = (s1 & 3) ^ (r1 & 3) ^ ((r1 >> 2) & 3);
    const bf16* gA0 = A + (size_t)(bm + r0) * K + p0 * 8;
    const bf16* gA1 = A + (size_t)(bm + r1) * K + p1 * 8;
    const bf16* gB0 = Bcat + (size_t)(bn + r0) * K + p0 * 8;
    const bf16* gB1 = Bcat + (size_t)(bn + r1) * K + p1 * 8;
    bf16* lA0 = As + s0 * 8;
    bf16* lA1 = As + s1 * 8;
    bf16* lB0 = Bs + s0 * 8;
    bf16* lB1 = Bs + s1 * 8;

    const int fr = lane & 15;
    const int fkc = lane >> 4;
    const int xsw = fkc ^ (fr & 3) ^ ((fr >> 2) & 3);

    for (int k0 = 0; k0 < K; k0 += BK) {
        __builtin_amdgcn_global_load_lds(
            (const __attribute__((address_space(1))) void*)(gA0 + k0),
            (__attribute__((address_space(3))) void*)lA0, 16, 0, 0);
        __builtin_amdgcn_global_load_lds(
            (const __attribute__((address_space(1))) void*)(gA1 + k0),
            (__attribute__((address_space(3))) void*)lA1, 16, 0, 0);
        __builtin_amdgcn_global_load_lds(
            (const __attribute__((address_space(1))) void*)(gB0 + k0),
            (__attribute__((address_space(3))) void*)lB0, 16, 0, 0);
        __builtin_amdgcn_global_load_lds(
            (const __attribute__((address_space(1))) void*)(gB1 + k0),
            (__attribute__((address_space(3))) void*)lB1, 16, 0, 0);
        __syncthreads();

        bf16x8 af[4], bg[4];
        #pragma unroll
        for (int t = 0; t < 4; ++t) {
            af[t] = *(const bf16x8*)(As + (wm + t * 16 + fr) * BK + xsw * 8);
            bg[t] = *(const bf16x8*)(Bs + (wn + t * 16 + fr) * BK + xsw * 8);
        }
        #pragma unroll
        for (int i = 0; i < 4; ++i)
            #pragma unroll
            for (int j = 0; j < 4; ++j)
                acc[i][j] = __builtin_amdgcn_mfma_f32_16x16x32_bf16(
                    af[i], bg[j], acc[i][j], 0, 0, 0);
        __syncthreads();
    }

    const bool second = (bn >= dm);
    const int colbase = bn + wn - (second ? dm : 0);
    const float* bias = second ? bc : bv;
    float* o0 = second ? out0 : out1;
    float* o1 = second ? nullptr : out2;

    float bb[4];
    #pragma unroll
    for (int j = 0; j < 4; ++j) bb[j] = bias[colbase + j * 16 + fr];

    float* E = &Es[wave][0];
    const int quad = lane >> 4;
    const int cc = (lane & 15) * 4;

    #pragma unroll
    for (int i = 0; i < 4; ++i) {
        #pragma unroll
        for (int j = 0; j < 4; ++j)
            #pragma unroll
            for (int r = 0; r < 4; ++r)
                E[(quad * 4 + r) * 68 + j * 16 + fr] = acc[i][j][r] + bb[j];
        #pragma unroll
        for (int ph = 0; ph < 4; ++ph) {
            const int row = quad * 4 + ph;
            const float4 v = *(const float4*)(E + row * 68 + cc);
            const size_t gi = (size_t)(bm + wm + i * 16 + row) * dm + colbase + cc;
            *(float4*)(o0 + gi) = v;
            if (o1) *(float4*)(o1 + gi) = v;
        }
    }
}

// ---------------- fp32 fallback ----------------
__global__ __launch_bounds__(256) void gemm_f32_naive(
    const float* __restrict__ A, const float* __restrict__ B,
    const float* __restrict__ bias,
    float* __restrict__ C0, float* __restrict__ C1,
    int M, int N, int K)
{
    const size_t idx = (size_t)blockIdx.x * 256 + threadIdx.x;
    if (idx >= (size_t)M * N) return;
    const int row = (int)(idx / N), col = (int)(idx % N);
    const float* a = A + (size_t)row * K;
    const float* b = B + (size_t)col * K;
    float s = bias ? bias[col] : 0.0f;
    for (int k = 0; k < K; ++k) s += a[k] * b[k];
    C0[idx] = s;
    if (C1) C1[idx] = s;
}

// Math: softmax row-sums == 1 => out1 = out2 = value@Wv^T+bv,
// out0 = value@(Wo@Wv)^T + (Wo@bv+bo). 3 dispatches.
extern "C" void kernel_launch(void* const* d_in, const int* in_sizes, int n_in,
                              void* d_out, int out_size, void* d_ws, size_t ws_size,
                              hipStream_t stream)
{
    const float* value = (const float*)d_in[2];
    const float* Wv    = (const float*)d_in[7];
    const float* bv    = (const float*)d_in[8];
    const float* Wo    = (const float*)d_in[9];
    const float* bo    = (const float*)d_in[10];

    const int dm = in_sizes[8];
    const int M  = in_sizes[2] / dm;
    const size_t MN = (size_t)M * dm;

    float* out0 = (float*)d_out;
    float* out1 = out0 + MN;
    float* out2 = out1 + MN;

    const size_t dm2 = (size_t)dm * dm;
    // ws: value_b | Wv_b | Wc_b (contig pair = Bcat) | Wo_b | WvT_b | bc
    const size_t need = MN * 2 + dm2 * 2 * 4 + (size_t)dm * 4;
    const bool ok = (ws_size >= need) && (M % TM == 0) && (dm % TM == 0) &&
                    (MN % 2048 == 0) && (dm2 % 2048 == 0) &&
                    (dm % 64 == 0) && (dm % 4 == 0);
    if (ok) {
        char* ws = (char*)d_ws;
        bf16* value_b = (bf16*)ws;   ws += MN * 2;
        bf16* Wv_b    = (bf16*)ws;   ws += dm2 * 2;
        bf16* Wc_b    = (bf16*)ws;   ws += dm2 * 2;
        bf16* Wo_b    = (bf16*)ws;   ws += dm2 * 2;
        bf16* WvT_b   = (bf16*)ws;   ws += dm2 * 2;
        float* bc     = (float*)ws;

        const int nbVal = (int)(MN / 2048);
        const int nbWv  = (int)(dm2 / 2048);
        const int nbWo  = nbWv;
        const int nbT   = (dm / 32) * (dm / 32);
        const int nbBc  = dm / 4;
        prep_kernel<<<nbVal + nbWv + nbWo + nbT + nbBc, 256, 0, stream>>>(
            value, Wv, Wo, bv, bo, value_b, Wv_b, Wo_b, WvT_b, bc,
            nbVal, nbWv, nbWo, nbT, dm);

        dim3 gwc(dm / 64, dm / 64);
        wc_gemm<<<gwc, 256, 0, stream>>>(Wo_b, WvT_b, Wc_b, dm, dm);

        dim3 grid(M / TM, 2 * dm / TN);
        gemm_fused<<<grid, 256, 0, stream>>>(value_b, Wv_b, bv, bc,
                                             out0, out1, out2, M, dm);
    } else {
        const int nblk = (int)((MN + 255) / 256);
        gemm_f32_naive<<<nblk, 256, 0, stream>>>(value, Wv, bv, out1, out2, M, dm, dm);
        gemm_f32_naive<<<nblk, 256, 0, stream>>>(out1, Wo, bo, out0, nullptr, M, dm, dm);
    }
}

// Round 5
// 154.156 us; speedup vs baseline: 1.2386x; 1.0379x over previous
//
#include <hip/hip_runtime.h>
#include <hip/hip_bf16.h>
#include <stdint.h>

using bf16 = __hip_bfloat16;
typedef __attribute__((ext_vector_type(8))) __bf16 bf16x8;
typedef __attribute__((ext_vector_type(4))) float f32x4;

static __device__ __forceinline__ bf16 f2b(float x) { return __float2bfloat16(x); }
static __device__ __forceinline__ uint32_t pack2(float a, float b) {
    bf16 ha = f2b(a), hb = f2b(b);
    return (uint32_t)(*(const uint16_t*)&ha) | ((uint32_t)(*(const uint16_t*)&hb) << 16);
}

// =====================================================================
// Dispatch 1 (prep_w): ONLY what wc_gemm needs (16 MB traffic):
//  [0,nbWo)  Wo fp32->bf16 (8/thread)
//  [+nbT)    Wv 32x32 tile: cast -> Wv_b (straight) AND WvT_b (transposed)
// =====================================================================
__global__ __launch_bounds__(256) void prep_w_kernel(
    const float* __restrict__ Wv, const float* __restrict__ Wo,
    bf16* __restrict__ Wv_b, bf16* __restrict__ Wo_b, bf16* __restrict__ WvT_b,
    int nbWo, int dm)
{
    __shared__ bf16 tile[32][34];
    const int b = blockIdx.x;
    const int tid = threadIdx.x;

    if (b < nbWo) {
        const size_t i = ((size_t)b * 256 + tid) * 8;
        const float4 v0 = *(const float4*)(Wo + i);
        const float4 v1 = *(const float4*)(Wo + i + 4);
        uint4 u = { pack2(v0.x, v0.y), pack2(v0.z, v0.w),
                    pack2(v1.x, v1.y), pack2(v1.z, v1.w) };
        *(uint4*)(Wo_b + i) = u;
    } else {
        const int t = b - nbWo;
        const int tpr = dm / 32;
        const int i0 = (t / tpr) * 32, j0 = (t % tpr) * 32;
        const int tx = tid & 31, ty = tid >> 5;      // ty 0..7
        #pragma unroll
        for (int p = 0; p < 4; ++p) {
            const int r = ty + p * 8;
            const bf16 h = f2b(Wv[(size_t)(i0 + r) * dm + j0 + tx]);
            Wv_b[(size_t)(i0 + r) * dm + j0 + tx] = h;
            tile[r][tx] = h;
        }
        __syncthreads();
        #pragma unroll
        for (int p = 0; p < 4; ++p) {
            const int c = ty + p * 8;
            WvT_b[(size_t)(j0 + c) * dm + i0 + tx] = tile[tx][c];
        }
    }
}

// =====================================================================
// Dispatch 2 (mix): wc blocks FIRST (long poles), then bandwidth blocks
// that overlap with them:
//  [0,nbWc)   Wc = Wo @ Wv : 64x64 tile, BK=64, global_load_lds w16,
//             XOR swizzle (slot s, row r=s>>3 stores part (s&7)^(r&7)).
//  [+nbVal)   value fp32->bf16 (8/thread)
//  [+nbBc)    bc[i] = Wo[i,:].bv + bo[i]  (4 rows/block, 1 row/wave)
// =====================================================================
__global__ __launch_bounds__(256, 4) void mix_kernel(
    const bf16* __restrict__ A, const bf16* __restrict__ B,   // Wo_b, WvT_b
    const float* __restrict__ value, const float* __restrict__ Wo,
    const float* __restrict__ bv, const float* __restrict__ bo,
    bf16* __restrict__ Wc_b, bf16* __restrict__ value_b, float* __restrict__ bc,
    int nbWc, int nbVal, int dm)
{
    __shared__ bf16 As[64 * 64];   // 8 KB (wc branch only)
    __shared__ bf16 Bs[64 * 64];

    const int blk = blockIdx.x;
    const int tid = threadIdx.x;

    if (blk < nbWc) {
        const int K = dm, N = dm;
        const int tpr = dm / 64;
        const int bm = (blk / tpr) * 64, bn = (blk % tpr) * 64;
        const int lane = tid & 63;
        const int wave = tid >> 6;
        const int wm = (wave >> 1) * 32;
        const int wn = (wave & 1) * 32;

        f32x4 acc[2][2] = {};

        const int s0 = wave * 128 + lane;
        const int s1 = s0 + 64;
        const int r0 = s0 >> 3, r1 = s1 >> 3;
        const int p0 = (s0 & 7) ^ (r0 & 7);
        const int p1 = (s1 & 7) ^ (r1 & 7);
        const bf16* gA0 = A + (size_t)(bm + r0) * K + p0 * 8;
        const bf16* gA1 = A + (size_t)(bm + r1) * K + p1 * 8;
        const bf16* gB0 = B + (size_t)(bn + r0) * K + p0 * 8;
        const bf16* gB1 = B + (size_t)(bn + r1) * K + p1 * 8;
        bf16* lA0 = As + s0 * 8;
        bf16* lA1 = As + s1 * 8;
        bf16* lB0 = Bs + s0 * 8;
        bf16* lB1 = Bs + s1 * 8;

        const int fr = lane & 15;
        const int fkc = lane >> 4;

        for (int k0 = 0; k0 < K; k0 += 64) {
            __builtin_amdgcn_global_load_lds(
                (const __attribute__((address_space(1))) void*)(gA0 + k0),
                (__attribute__((address_space(3))) void*)lA0, 16, 0, 0);
            __builtin_amdgcn_global_load_lds(
                (const __attribute__((address_space(1))) void*)(gA1 + k0),
                (__attribute__((address_space(3))) void*)lA1, 16, 0, 0);
            __builtin_amdgcn_global_load_lds(
                (const __attribute__((address_space(1))) void*)(gB0 + k0),
                (__attribute__((address_space(3))) void*)lB0, 16, 0, 0);
            __builtin_amdgcn_global_load_lds(
                (const __attribute__((address_space(1))) void*)(gB1 + k0),
                (__attribute__((address_space(3))) void*)lB1, 16, 0, 0);
            __syncthreads();

            #pragma unroll
            for (int kk = 0; kk < 2; ++kk) {
                const int xsw = ((kk * 4 + fkc) ^ (fr & 7)) * 8;
                bf16x8 af[2], bg[2];
                #pragma unroll
                for (int u = 0; u < 2; ++u) {
                    af[u] = *(const bf16x8*)(As + (wm + u * 16 + fr) * 64 + xsw);
                    bg[u] = *(const bf16x8*)(Bs + (wn + u * 16 + fr) * 64 + xsw);
                }
                #pragma unroll
                for (int i = 0; i < 2; ++i)
                    #pragma unroll
                    for (int j = 0; j < 2; ++j)
                        acc[i][j] = __builtin_amdgcn_mfma_f32_16x16x32_bf16(
                            af[i], bg[j], acc[i][j], 0, 0, 0);
            }
            __syncthreads();
        }

        const int quad = lane >> 4;
        #pragma unroll
        for (int j = 0; j < 2; ++j) {
            const int col = bn + wn + j * 16 + fr;
            #pragma unroll
            for (int i = 0; i < 2; ++i) {
                const int row0 = bm + wm + i * 16 + quad * 4;
                #pragma unroll
                for (int r = 0; r < 4; ++r)
                    Wc_b[(size_t)(row0 + r) * N + col] = f2b(acc[i][j][r]);
            }
        }
    } else if (blk < nbWc + nbVal) {
        const size_t i = ((size_t)(blk - nbWc) * 256 + tid) * 8;
        const float4 v0 = *(const float4*)(value + i);
        const float4 v1 = *(const float4*)(value + i + 4);
        uint4 u = { pack2(v0.x, v0.y), pack2(v0.z, v0.w),
                    pack2(v1.x, v1.y), pack2(v1.z, v1.w) };
        *(uint4*)(value_b + i) = u;
    } else {
        const int lane = tid & 63;
        const int wave = tid >> 6;
        const int row = (blk - nbWc - nbVal) * 4 + wave;
        const float* wrow = Wo + (size_t)row * dm;
        float s = 0.f;
        for (int k = lane * 4; k < dm; k += 256) {
            const float4 w = *(const float4*)(wrow + k);
            const float4 x = *(const float4*)(bv + k);
            s += w.x * x.x + w.y * x.y + w.z * x.z + w.w * x.w;
        }
        #pragma unroll
        for (int off = 32; off >= 1; off >>= 1) s += __shfl_down(s, off, 64);
        if (lane == 0) bc[row] = s + bo[row];
    }
}

// =====================================================================
// Dispatch 3: big fused GEMM (R3/R4 structure, unchanged math):
// C = value_b @ Bcat^T, Bcat=[Wv_b;Wc_b]. bn<dm -> out1&out2 (+bv);
// bn>=dm -> out0 (+bc). XOR-swizzled LDS staging + padded-LDS float4
// epilogue. __launch_bounds__(256,4): 4 blocks/CU (VGPR<=128).
// =====================================================================
#define TM 128
#define TN 128
#define BK 32

__global__ __launch_bounds__(256, 4) void gemm_fused(
    const bf16* __restrict__ A, const bf16* __restrict__ Bcat,
    const float* __restrict__ bv, const float* __restrict__ bc,
    float* __restrict__ out0, float* __restrict__ out1, float* __restrict__ out2,
    int M, int dm)
{
    __shared__ bf16 As[TM * BK];
    __shared__ bf16 Bs[TN * BK];
    __shared__ float Es[4][16 * 68];

    const int K = dm;
    const int tid = threadIdx.x;
    const int lane = tid & 63;
    const int wave = tid >> 6;
    const int wm = (wave >> 1) * 64;
    const int wn = (wave & 1) * 64;
    const int bm = blockIdx.x * TM;
    const int bn = blockIdx.y * TN;

    f32x4 acc[4][4] = {};

    const int s0 = wave * 128 + lane;
    const int s1 = s0 + 64;
    const int r0 = s0 >> 2, r1 = s1 >> 2;
    const int p0 = (s0 & 3) ^ (r0 & 3) ^ ((r0 >> 2) & 3);
    const int p1 = (s1 & 3) ^ (r1 & 3) ^ ((r1 >> 2) & 3);
    const bf16* gA0 = A + (size_t)(bm + r0) * K + p0 * 8;
    const bf16* gA1 = A + (size_t)(bm + r1) * K + p1 * 8;
    const bf16* gB0 = Bcat + (size_t)(bn + r0) * K + p0 * 8;
    const bf16* gB1 = Bcat + (size_t)(bn + r1) * K + p1 * 8;
    bf16* lA0 = As + s0 * 8;
    bf16* lA1 = As + s1 * 8;
    bf16* lB0 = Bs + s0 * 8;
    bf16* lB1 = Bs + s1 * 8;

    const int fr = lane & 15;
    const int fkc = lane >> 4;
    const int xsw = fkc ^ (fr & 3) ^ ((fr >> 2) & 3);

    for (int k0 = 0; k0 < K; k0 += BK) {
        __builtin_amdgcn_global_load_lds(
            (const __attribute__((address_space(1))) void*)(gA0 + k0),
            (__attribute__((address_space(3))) void*)lA0, 16, 0, 0);
        __builtin_amdgcn_global_load_lds(
            (const __attribute__((address_space(1))) void*)(gA1 + k0),
            (__attribute__((address_space(3))) void*)lA1, 16, 0, 0);
        __builtin_amdgcn_global_load_lds(
            (const __attribute__((address_space(1))) void*)(gB0 + k0),
            (__attribute__((address_space(3))) void*)lB0, 16, 0, 0);
        __builtin_amdgcn_global_load_lds(
            (const __attribute__((address_space(1))) void*)(gB1 + k0),
            (__attribute__((address_space(3))) void*)lB1, 16, 0, 0);
        __syncthreads();

        bf16x8 af[4], bg[4];
        #pragma unroll
        for (int t = 0; t < 4; ++t) {
            af[t] = *(const bf16x8*)(As + (wm + t * 16 + fr) * BK + xsw * 8);
            bg[t] = *(const bf16x8*)(Bs + (wn + t * 16 + fr) * BK + xsw * 8);
        }
        #pragma unroll
        for (int i = 0; i < 4; ++i)
            #pragma unroll
            for (int j = 0; j < 4; ++j)
                acc[i][j] = __builtin_amdgcn_mfma_f32_16x16x32_bf16(
                    af[i], bg[j], acc[i][j], 0, 0, 0);
        __syncthreads();
    }

    const bool second = (bn >= dm);
    const int colbase = bn + wn - (second ? dm : 0);
    const float* bias = second ? bc : bv;
    float* o0 = second ? out0 : out1;
    float* o1 = second ? nullptr : out2;

    float bb[4];
    #pragma unroll
    for (int j = 0; j < 4; ++j) bb[j] = bias[colbase + j * 16 + fr];

    float* E = &Es[wave][0];
    const int quad = lane >> 4;
    const int cc = (lane & 15) * 4;

    #pragma unroll
    for (int i = 0; i < 4; ++i) {
        #pragma unroll
        for (int j = 0; j < 4; ++j)
            #pragma unroll
            for (int r = 0; r < 4; ++r)
                E[(quad * 4 + r) * 68 + j * 16 + fr] = acc[i][j][r] + bb[j];
        #pragma unroll
        for (int ph = 0; ph < 4; ++ph) {
            const int row = quad * 4 + ph;
            const float4 v = *(const float4*)(E + row * 68 + cc);
            const size_t gi = (size_t)(bm + wm + i * 16 + row) * dm + colbase + cc;
            *(float4*)(o0 + gi) = v;
            if (o1) *(float4*)(o1 + gi) = v;
        }
    }
}

// ---------------- fp32 fallback ----------------
__global__ __launch_bounds__(256) void gemm_f32_naive(
    const float* __restrict__ A, const float* __restrict__ B,
    const float* __restrict__ bias,
    float* __restrict__ C0, float* __restrict__ C1,
    int M, int N, int K)
{
    const size_t idx = (size_t)blockIdx.x * 256 + threadIdx.x;
    if (idx >= (size_t)M * N) return;
    const int row = (int)(idx / N), col = (int)(idx % N);
    const float* a = A + (size_t)row * K;
    const float* b = B + (size_t)col * K;
    float s = bias ? bias[col] : 0.0f;
    for (int k = 0; k < K; ++k) s += a[k] * b[k];
    C0[idx] = s;
    if (C1) C1[idx] = s;
}

// Math: softmax row-sums == 1 => out1 = out2 = value@Wv^T+bv,
// out0 = value@(Wo@Wv)^T + (Wo@bv+bo).
// Pipeline: (1) Wo/Wv casts+transpose (16MB), (2) Wc-GEMM overlapped with
// value cast + bc, (3) one 4096x2048x1024 bf16 GEMM.
extern "C" void kernel_launch(void* const* d_in, const int* in_sizes, int n_in,
                              void* d_out, int out_size, void* d_ws, size_t ws_size,
                              hipStream_t stream)
{
    const float* value = (const float*)d_in[2];
    const float* Wv    = (const float*)d_in[7];
    const float* bv    = (const float*)d_in[8];
    const float* Wo    = (const float*)d_in[9];
    const float* bo    = (const float*)d_in[10];

    const int dm = in_sizes[8];
    const int M  = in_sizes[2] / dm;
    const size_t MN = (size_t)M * dm;

    float* out0 = (float*)d_out;
    float* out1 = out0 + MN;
    float* out2 = out1 + MN;

    const size_t dm2 = (size_t)dm * dm;
    // ws: value_b | Wv_b | Wc_b (contig pair = Bcat) | Wo_b | WvT_b | bc
    const size_t need = MN * 2 + dm2 * 2 * 4 + (size_t)dm * 4;
    const bool ok = (ws_size >= need) && (M % TM == 0) && (dm % TM == 0) &&
                    (MN % 2048 == 0) && (dm2 % 2048 == 0) &&
                    (dm % 64 == 0) && (dm % 4 == 0);
    if (ok) {
        char* ws = (char*)d_ws;
        bf16* value_b = (bf16*)ws;   ws += MN * 2;
        bf16* Wv_b    = (bf16*)ws;   ws += dm2 * 2;
        bf16* Wc_b    = (bf16*)ws;   ws += dm2 * 2;
        bf16* Wo_b    = (bf16*)ws;   ws += dm2 * 2;
        bf16* WvT_b   = (bf16*)ws;   ws += dm2 * 2;
        float* bc     = (float*)ws;

        const int nbWo  = (int)(dm2 / 2048);
        const int nbT   = (dm / 32) * (dm / 32);
        prep_w_kernel<<<nbWo + nbT, 256, 0, stream>>>(
            Wv, Wo, Wv_b, Wo_b, WvT_b, nbWo, dm);

        const int nbWc  = (dm / 64) * (dm / 64);
        const int nbVal = (int)(MN / 2048);
        const int nbBc  = dm / 4;
        mix_kernel<<<nbWc + nbVal + nbBc, 256, 0, stream>>>(
            Wo_b, WvT_b, value, Wo, bv, bo, Wc_b, value_b, bc,
            nbWc, nbVal, dm);

        dim3 grid(M / TM, 2 * dm / TN);
        gemm_fused<<<grid, 256, 0, stream>>>(value_b, Wv_b, bv, bc,
                                             out0, out1, out2, M, dm);
    } else {
        const int nblk = (int)((MN + 255) / 256);
        gemm_f32_naive<<<nblk, 256, 0, stream>>>(value, Wv, bv, out1, out2, M, dm, dm);
        gemm_f32_naive<<<nblk, 256, 0, stream>>>(out1, Wo, bo, out0, nullptr, M, dm, dm);
    }
}

// Round 6
// 150.626 us; speedup vs baseline: 1.2676x; 1.0234x over previous
//
#include <hip/hip_runtime.h>
#include <hip/hip_bf16.h>
#include <stdint.h>

using bf16 = __hip_bfloat16;
typedef __attribute__((ext_vector_type(8))) __bf16 bf16x8;
typedef __attribute__((ext_vector_type(4))) float f32x4;

static __device__ __forceinline__ bf16 f2b(float x) { return __float2bfloat16(x); }
static __device__ __forceinline__ uint32_t pack2(float a, float b) {
    bf16 ha = f2b(a), hb = f2b(b);
    return (uint32_t)(*(const uint16_t*)&ha) | ((uint32_t)(*(const uint16_t*)&hb) << 16);
}

// =====================================================================
// Dispatch 1: Wv only (8 MB): 32x32 tile cast -> Wv_b AND WvT_b.
// =====================================================================
__global__ __launch_bounds__(256) void prep_w_kernel(
    const float* __restrict__ Wv,
    bf16* __restrict__ Wv_b, bf16* __restrict__ WvT_b, int dm)
{
    __shared__ bf16 tile[32][34];
    const int t = blockIdx.x;
    const int tid = threadIdx.x;
    const int tpr = dm / 32;
    const int i0 = (t / tpr) * 32, j0 = (t % tpr) * 32;
    const int tx = tid & 31, ty = tid >> 5;      // ty 0..7
    #pragma unroll
    for (int p = 0; p < 4; ++p) {
        const int r = ty + p * 8;
        const bf16 h = f2b(Wv[(size_t)(i0 + r) * dm + j0 + tx]);
        Wv_b[(size_t)(i0 + r) * dm + j0 + tx] = h;
        tile[r][tx] = h;
    }
    __syncthreads();
    #pragma unroll
    for (int p = 0; p < 4; ++p) {
        const int c = ty + p * 8;
        WvT_b[(size_t)(j0 + c) * dm + i0 + tx] = tile[tx][c];
    }
}

// =====================================================================
// Dispatch 2 (mix): wc blocks first, then bandwidth blocks overlapping:
//  [0,nbWc)   Wc = Wo @ Wv : 64x64 tile, BK=64. A staged from fp32 Wo
//             (float4 x2 -> pack -> swizzled ds_write_b128); B = WvT_b via
//             global_load_lds w16. XOR swizzle: slot s (r=s>>3) holds part
//             (s&7)^(r&7); reader q=((kk*4+fkc)^(fr&7)) -> conflict-free.
//  [+nbVal)   value fp32->bf16 (8/thread)
//  [+nbBc)    bc[i] = Wo[i,:].bv + bo[i]  (4 rows/block, 1 row/wave)
// =====================================================================
__global__ __launch_bounds__(256, 4) void mix_kernel(
    const bf16* __restrict__ B,                     // WvT_b
    const float* __restrict__ value, const float* __restrict__ Wo,
    const float* __restrict__ bv, const float* __restrict__ bo,
    bf16* __restrict__ Wc_b, bf16* __restrict__ value_b, float* __restrict__ bc,
    int nbWc, int nbVal, int dm)
{
    __shared__ bf16 As[64 * 64];   // 8 KB (wc branch only)
    __shared__ bf16 Bs[64 * 64];

    const int blk = blockIdx.x;
    const int tid = threadIdx.x;

    if (blk < nbWc) {
        const int K = dm, N = dm;
        const int tpr = dm / 64;
        const int bm = (blk / tpr) * 64, bn = (blk % tpr) * 64;
        const int lane = tid & 63;
        const int wave = tid >> 6;
        const int wm = (wave >> 1) * 32;
        const int wn = (wave & 1) * 32;

        f32x4 acc[2][2] = {};

        // B staging (global_load_lds, 2 slots/lane)
        const int s0 = wave * 128 + lane;
        const int s1 = s0 + 64;
        const int r0 = s0 >> 3, r1 = s1 >> 3;
        const int p0 = (s0 & 7) ^ (r0 & 7);
        const int p1 = (s1 & 7) ^ (r1 & 7);
        const bf16* gB0 = B + (size_t)(bn + r0) * K + p0 * 8;
        const bf16* gB1 = B + (size_t)(bn + r1) * K + p1 * 8;
        bf16* lB0 = Bs + s0 * 8;
        bf16* lB1 = Bs + s1 * 8;

        // A staging from fp32 (2 slots/thread: tid, tid+256)
        const int sa0 = tid, sa1 = tid + 256;
        const int ra0 = sa0 >> 3, pa0 = (sa0 & 7) ^ (ra0 & 7);
        const int ra1 = sa1 >> 3, pa1 = (sa1 & 7) ^ (ra1 & 7);
        const float* gA0 = Wo + (size_t)(bm + ra0) * K + pa0 * 8;
        const float* gA1 = Wo + (size_t)(bm + ra1) * K + pa1 * 8;

        const int fr = lane & 15;
        const int fkc = lane >> 4;
        const int xb = fr & 7;

        for (int k0 = 0; k0 < K; k0 += 64) {
            __builtin_amdgcn_global_load_lds(
                (const __attribute__((address_space(1))) void*)(gB0 + k0),
                (__attribute__((address_space(3))) void*)lB0, 16, 0, 0);
            __builtin_amdgcn_global_load_lds(
                (const __attribute__((address_space(1))) void*)(gB1 + k0),
                (__attribute__((address_space(3))) void*)lB1, 16, 0, 0);
            const float4 a0 = *(const float4*)(gA0 + k0);
            const float4 a1 = *(const float4*)(gA0 + k0 + 4);
            const float4 a2 = *(const float4*)(gA1 + k0);
            const float4 a3 = *(const float4*)(gA1 + k0 + 4);
            uint4 u0 = { pack2(a0.x, a0.y), pack2(a0.z, a0.w),
                         pack2(a1.x, a1.y), pack2(a1.z, a1.w) };
            uint4 u1 = { pack2(a2.x, a2.y), pack2(a2.z, a2.w),
                         pack2(a3.x, a3.y), pack2(a3.z, a3.w) };
            *(uint4*)(As + sa0 * 8) = u0;
            *(uint4*)(As + sa1 * 8) = u1;
            __syncthreads();

            #pragma unroll
            for (int kk = 0; kk < 2; ++kk) {
                const int xsw = ((kk * 4 + fkc) ^ xb) * 8;
                bf16x8 af[2], bg[2];
                #pragma unroll
                for (int u = 0; u < 2; ++u) {
                    af[u] = *(const bf16x8*)(As + (wm + u * 16 + fr) * 64 + xsw);
                    bg[u] = *(const bf16x8*)(Bs + (wn + u * 16 + fr) * 64 + xsw);
                }
                #pragma unroll
                for (int i = 0; i < 2; ++i)
                    #pragma unroll
                    for (int j = 0; j < 2; ++j)
                        acc[i][j] = __builtin_amdgcn_mfma_f32_16x16x32_bf16(
                            af[i], bg[j], acc[i][j], 0, 0, 0);
            }
            __syncthreads();
        }

        const int quad = lane >> 4;
        #pragma unroll
        for (int j = 0; j < 2; ++j) {
            const int col = bn + wn + j * 16 + fr;
            #pragma unroll
            for (int i = 0; i < 2; ++i) {
                const int row0 = bm + wm + i * 16 + quad * 4;
                #pragma unroll
                for (int r = 0; r < 4; ++r)
                    Wc_b[(size_t)(row0 + r) * N + col] = f2b(acc[i][j][r]);
            }
        }
    } else if (blk < nbWc + nbVal) {
        const size_t i = ((size_t)(blk - nbWc) * 256 + tid) * 8;
        const float4 v0 = *(const float4*)(value + i);
        const float4 v1 = *(const float4*)(value + i + 4);
        uint4 u = { pack2(v0.x, v0.y), pack2(v0.z, v0.w),
                    pack2(v1.x, v1.y), pack2(v1.z, v1.w) };
        *(uint4*)(value_b + i) = u;
    } else {
        const int lane = tid & 63;
        const int wave = tid >> 6;
        const int row = (blk - nbWc - nbVal) * 4 + wave;
        const float* wrow = Wo + (size_t)row * dm;
        float s = 0.f;
        for (int k = lane * 4; k < dm; k += 256) {
            const float4 w = *(const float4*)(wrow + k);
            const float4 x = *(const float4*)(bv + k);
            s += w.x * x.x + w.y * x.y + w.z * x.z + w.w * x.w;
        }
        #pragma unroll
        for (int off = 32; off >= 1; off >>= 1) s += __shfl_down(s, off, 64);
        if (lane == 0) bc[row] = s + bo[row];
    }
}

// =====================================================================
// Dispatch 3: big fused GEMM, BK=64 (16 k-iters, half the barrier drains).
// C = value_b @ Bcat^T, Bcat=[Wv_b;Wc_b]. bn<dm -> out1&out2 (+bv);
// bn>=dm -> out0 (+bc). Swizzle: slot s (row r=s>>3, 8x16B parts/row)
// holds part (s&7)^(r&7); reader q=((kk*4+fkc)^(fr&7)) -> 8 distinct
// bank-quads per 8-lane group (conflict-free). Padded-LDS f4 epilogue.
// =====================================================================
#define TM 128
#define TN 128
#define BK 64

__global__ __launch_bounds__(256, 2) void gemm_fused(
    const bf16* __restrict__ A, const bf16* __restrict__ Bcat,
    const float* __restrict__ bv, const float* __restrict__ bc,
    float* __restrict__ out0, float* __restrict__ out1, float* __restrict__ out2,
    int M, int dm)
{
    __shared__ bf16 As[TM * BK];          // 16 KB
    __shared__ bf16 Bs[TN * BK];          // 16 KB
    __shared__ float Es[4][16 * 68];      // 17 KB epilogue staging

    const int K = dm;
    const int tid = threadIdx.x;
    const int lane = tid & 63;
    const int wave = tid >> 6;
    const int wm = (wave >> 1) * 64;
    const int wn = (wave & 1) * 64;
    const int bm = blockIdx.x * TM;
    const int bn = blockIdx.y * TN;

    f32x4 acc[4][4] = {};

    // 4 slots per wave per matrix (1024 slots of 16 B per 16 KB tile)
    const bf16* gA[4]; const bf16* gB[4];
    bf16* lA[4]; bf16* lB[4];
    #pragma unroll
    for (int q = 0; q < 4; ++q) {
        const int s = wave * 256 + q * 64 + lane;
        const int r = s >> 3;
        const int p = (s & 7) ^ (r & 7);
        gA[q] = A + (size_t)(bm + r) * K + p * 8;
        gB[q] = Bcat + (size_t)(bn + r) * K + p * 8;
        lA[q] = As + s * 8;
        lB[q] = Bs + s * 8;
    }

    const int fr = lane & 15;
    const int fkc = lane >> 4;
    const int xb = fr & 7;

    for (int k0 = 0; k0 < K; k0 += BK) {
        #pragma unroll
        for (int q = 0; q < 4; ++q)
            __builtin_amdgcn_global_load_lds(
                (const __attribute__((address_space(1))) void*)(gA[q] + k0),
                (__attribute__((address_space(3))) void*)lA[q], 16, 0, 0);
        #pragma unroll
        for (int q = 0; q < 4; ++q)
            __builtin_amdgcn_global_load_lds(
                (const __attribute__((address_space(1))) void*)(gB[q] + k0),
                (__attribute__((address_space(3))) void*)lB[q], 16, 0, 0);
        __syncthreads();

        #pragma unroll
        for (int kk = 0; kk < 2; ++kk) {
            const int xsw = ((kk * 4 + fkc) ^ xb) * 8;
            bf16x8 af[4], bg[4];
            #pragma unroll
            for (int t = 0; t < 4; ++t) {
                af[t] = *(const bf16x8*)(As + (wm + t * 16 + fr) * BK + xsw);
                bg[t] = *(const bf16x8*)(Bs + (wn + t * 16 + fr) * BK + xsw);
            }
            #pragma unroll
            for (int i = 0; i < 4; ++i)
                #pragma unroll
                for (int j = 0; j < 4; ++j)
                    acc[i][j] = __builtin_amdgcn_mfma_f32_16x16x32_bf16(
                        af[i], bg[j], acc[i][j], 0, 0, 0);
        }
        __syncthreads();
    }

    const bool second = (bn >= dm);
    const int colbase = bn + wn - (second ? dm : 0);
    const float* bias = second ? bc : bv;
    float* o0 = second ? out0 : out1;
    float* o1 = second ? nullptr : out2;

    float bb[4];
    #pragma unroll
    for (int j = 0; j < 4; ++j) bb[j] = bias[colbase + j * 16 + fr];

    float* E = &Es[wave][0];
    const int quad = lane >> 4;
    const int cc = (lane & 15) * 4;

    #pragma unroll
    for (int i = 0; i < 4; ++i) {
        #pragma unroll
        for (int j = 0; j < 4; ++j)
            #pragma unroll
            for (int r = 0; r < 4; ++r)
                E[(quad * 4 + r) * 68 + j * 16 + fr] = acc[i][j][r] + bb[j];
        #pragma unroll
        for (int ph = 0; ph < 4; ++ph) {
            const int row = quad * 4 + ph;
            const float4 v = *(const float4*)(E + row * 68 + cc);
            const size_t gi = (size_t)(bm + wm + i * 16 + row) * dm + colbase + cc;
            *(float4*)(o0 + gi) = v;
            if (o1) *(float4*)(o1 + gi) = v;
        }
    }
}

// ---------------- fp32 fallback ----------------
__global__ __launch_bounds__(256) void gemm_f32_naive(
    const float* __restrict__ A, const float* __restrict__ B,
    const float* __restrict__ bias,
    float* __restrict__ C0, float* __restrict__ C1,
    int M, int N, int K)
{
    const size_t idx = (size_t)blockIdx.x * 256 + threadIdx.x;
    if (idx >= (size_t)M * N) return;
    const int row = (int)(idx / N), col = (int)(idx % N);
    const float* a = A + (size_t)row * K;
    const float* b = B + (size_t)col * K;
    float s = bias ? bias[col] : 0.0f;
    for (int k = 0; k < K; ++k) s += a[k] * b[k];
    C0[idx] = s;
    if (C1) C1[idx] = s;
}

// Math: softmax row-sums == 1 => out1 = out2 = value@Wv^T+bv,
// out0 = value@(Wo@Wv)^T + (Wo@bv+bo).
// Pipeline: (1) Wv cast+transpose (8MB), (2) Wc-GEMM (fp32 A direct)
// overlapped with value cast + bc, (3) one 4096x2048x1024 bf16 GEMM, BK=64.
extern "C" void kernel_launch(void* const* d_in, const int* in_sizes, int n_in,
                              void* d_out, int out_size, void* d_ws, size_t ws_size,
                              hipStream_t stream)
{
    const float* value = (const float*)d_in[2];
    const float* Wv    = (const float*)d_in[7];
    const float* bv    = (const float*)d_in[8];
    const float* Wo    = (const float*)d_in[9];
    const float* bo    = (const float*)d_in[10];

    const int dm = in_sizes[8];
    const int M  = in_sizes[2] / dm;
    const size_t MN = (size_t)M * dm;

    float* out0 = (float*)d_out;
    float* out1 = out0 + MN;
    float* out2 = out1 + MN;

    const size_t dm2 = (size_t)dm * dm;
    // ws: value_b | Wv_b | Wc_b (contig pair = Bcat) | WvT_b | bc
    const size_t need = MN * 2 + dm2 * 2 * 3 + (size_t)dm * 4;
    const bool ok = (ws_size >= need) && (M % TM == 0) && (dm % TM == 0) &&
                    (MN % 2048 == 0) && (dm2 % 2048 == 0) &&
                    (dm % 64 == 0) && (dm % 4 == 0);
    if (ok) {
        char* ws = (char*)d_ws;
        bf16* value_b = (bf16*)ws;   ws += MN * 2;
        bf16* Wv_b    = (bf16*)ws;   ws += dm2 * 2;
        bf16* Wc_b    = (bf16*)ws;   ws += dm2 * 2;
        bf16* WvT_b   = (bf16*)ws;   ws += dm2 * 2;
        float* bc     = (float*)ws;

        const int nbT = (dm / 32) * (dm / 32);
        prep_w_kernel<<<nbT, 256, 0, stream>>>(Wv, Wv_b, WvT_b, dm);

        const int nbWc  = (dm / 64) * (dm / 64);
        const int nbVal = (int)(MN / 2048);
        const int nbBc  = dm / 4;
        mix_kernel<<<nbWc + nbVal + nbBc, 256, 0, stream>>>(
            WvT_b, value, Wo, bv, bo, Wc_b, value_b, bc,
            nbWc, nbVal, dm);

        dim3 grid(M / TM, 2 * dm / TN);
        gemm_fused<<<grid, 256, 0, stream>>>(value_b, Wv_b, bv, bc,
                                             out0, out1, out2, M, dm);
    } else {
        const int nblk = (int)((MN + 255) / 256);
        gemm_f32_naive<<<nblk, 256, 0, stream>>>(value, Wv, bv, out1, out2, M, dm, dm);
        gemm_f32_naive<<<nblk, 256, 0, stream>>>(out1, Wo, bo, out0, nullptr, M, dm, dm);
    }
}